// Round 15
// baseline (185.077 us; speedup 1.0000x reference)
//
#include <hip/hip_runtime.h>
#include <hip/hip_bf16.h>

// AttnBlock: GN -> QKV 1x1conv -> attention(n=4096,d=512) -> out-proj -> +x
// R15: fp8 e4m3 for S-GEMM and PV (non-scaled mfma_f32_16x16x32_fp8_fp8 =
// bf16 rate but HALF the operand bytes). PV was at the LDS-BW roofline
// (62/69 TB/s at MF=2 bf16) -> fp8 halves LDS traffic. BK=128 fp8 keeps
// 128-B LDS rows => staging/swizzle byte-identical to the proven kernels;
// fragments become ds_read_b64 (conflict-free: 2-way = free). s_gemm8f:
// 4 K-tiles x 4 phases (half the barriers). Q/K/VO quantized in qkvo
// epilogue; P written fp8 (32 MB); row sums from exact f32 acc.

typedef __attribute__((ext_vector_type(8))) short short8_t;
typedef __attribute__((ext_vector_type(4))) short short4_t;
typedef __attribute__((ext_vector_type(4))) float f32x4;

__device__ __forceinline__ void gload16(const void* g, void* l) {
  __builtin_amdgcn_global_load_lds(
      (const __attribute__((address_space(1))) void*)g,
      (__attribute__((address_space(3))) void*)l, 16, 0, 0);
}

__device__ __forceinline__ short f2bf_bits(float f) {
  __hip_bfloat16 h = __float2bfloat16(f);
  return *reinterpret_cast<short*>(&h);
}
__device__ __forceinline__ float bfbits2f(short s) {
  union { unsigned int u; float f; } c;
  c.u = ((unsigned int)(unsigned short)s) << 16;
  return c.f;
}

// float -> OCP e4m3 (RNE), finite inputs. max 448 = 0x7E; min subnorm 2^-9.
__device__ __forceinline__ unsigned char f2e4m3(float f) {
  union { float f; unsigned int u; } a; a.f = f;
  const unsigned char s = (a.u >> 24) & 0x80;
  a.u &= 0x7FFFFFFFu;
  if (a.f >= 448.f) return s | 0x7E;
  if (a.f < 0.0009765625f) return s;            // < 2^-10 -> 0
  const int exp = (int)(a.u >> 23) - 127;
  if (exp >= -6) {                               // normal
    unsigned int keep = (a.u >> 20) & 7;
    const unsigned int rest = a.u & 0xFFFFF;
    int e = exp;
    keep += (rest > 0x80000u) || (rest == 0x80000u && (keep & 1));
    if (keep == 8) { keep = 0; ++e; }
    unsigned int enc = ((unsigned int)(e + 7) << 3) | keep;
    if (enc >= 0x7F) enc = 0x7E;
    return s | (unsigned char)enc;
  }
  const float scaled = a.f * 512.f;              // subnormal: q * 2^-9
  int q = (int)(scaled + 0.5f);
  if (q >= 8) return s | 0x08;
  return s | (unsigned char)q;
}

// ---------------------------------------------------------------------------
// s_gemm8f: Punnorm[i][j] = exp2(c * Q[i].K[j]) in fp8, + per-(bn) row
// partials (f32, pre-quantization). fp8 inputs qk [z][4096][1024] bytes.
// 512 thr = 8 waves. Tile 256x256, BK=128 fp8 (128-B rows), 4 K-tiles x
// 4 phases. Same R12-proven schedule with nkt=4: ph1 stages B0,B1(t+1)
// [t in {1,2}]; ph2 A0(t+2), ph4 A1(t+2) [t<2]; vmcnt(4) end ph4 (t<2)
// retires exactly tile t+1's regions; vmcnt(0) at t==2.
// ---------------------------------------------------------------------------
__global__ __launch_bounds__(512)
void s_gemm8f(const unsigned char* __restrict__ qk,
              unsigned char* __restrict__ P, float* __restrict__ part2,
              float c)
{
  const long long QKz = 4096LL * 1024;
  const long long SS  = 4096LL * 4096;

  const int b = blockIdx.x;                 // 512 blocks: 16m x 16n x 2z
  const int bz = b >> 8;
  const int r = b & 255, xcd = r & 7, sl = r >> 3;
  const int bm = (xcd >> 1) * 4 + (sl & 3);
  const int bn = (xcd & 1) * 8 + (sl >> 2);

  const unsigned char* Aq = qk + (size_t)bz * QKz;
  const unsigned char* Bk = Aq + 512;

  const int tid = threadIdx.x;
  const int wid = tid >> 6, l = tid & 63;
  const int wrM = wid >> 2, wcN = wid & 3;
  const int lhi = l >> 4, llo = l & 15;

  __shared__ char sm[2 * 65536];            // [buf][A 32KB | B 32KB]

  f32x4 acc[2][2][4][2] = {};               // [Mh][Nh][m][n]
  long long af[4][4], bf[2][4];             // [m][kk], [n][kk]

  const int rIn = l >> 3;
  const int colSw = 16 * ((l & 7) ^ (rIn & 7));   // bytes
  const unsigned char* gA = Aq + (size_t)(bm * 256 + rIn) * 1024 + colSw;
  const unsigned char* gB = Bk + (size_t)(bn * 256 + rIn) * 1024 + colSw;

  auto STG = [&](int mat, int half, int t) {
    const unsigned char* src = mat ? gB : gA;
    char* dst = sm + (t & 1) * 65536 + mat * 32768;
    const int rb = half * 128 + wid * 16;
    gload16(src + (size_t)rb * 1024 + t * 128, dst + rb * 128);
    gload16(src + (size_t)(rb + 8) * 1024 + t * 128, dst + (rb + 8) * 128);
  };

#define PHASE(MH, NH, LA, LB, VM, ...) do {                                   \
    const char* bbA = sm + bsel * 65536;                                      \
    const char* bbB = bbA + 32768;                                            \
    if (LA) {                                                                 \
      _Pragma("unroll") for (int m = 0; m < 4; ++m) {                         \
        const int rowA = (MH) * 128 + wrM * 64 + m * 16 + llo;                \
        _Pragma("unroll") for (int kk = 0; kk < 4; ++kk)                      \
          af[m][kk] = *(const long long*)(bbA + rowA * 128 +                  \
              (((kk * 2 + (lhi >> 1)) ^ (rowA & 7)) * 16) + (lhi & 1) * 8);   \
      }                                                                       \
    }                                                                         \
    if (LB) {                                                                 \
      _Pragma("unroll") for (int n = 0; n < 2; ++n) {                         \
        const int rowB = (NH) * 128 + wcN * 32 + n * 16 + llo;                \
        _Pragma("unroll") for (int kk = 0; kk < 4; ++kk)                      \
          bf[n][kk] = *(const long long*)(bbB + rowB * 128 +                  \
              (((kk * 2 + (lhi >> 1)) ^ (rowB & 7)) * 16) + (lhi & 1) * 8);   \
      }                                                                       \
    }                                                                         \
    __VA_ARGS__;                                                              \
    __builtin_amdgcn_s_barrier();                                             \
    __builtin_amdgcn_s_setprio(1);                                            \
    _Pragma("unroll") for (int kk = 0; kk < 4; ++kk)                          \
      _Pragma("unroll") for (int m = 0; m < 4; ++m)                           \
        _Pragma("unroll") for (int n = 0; n < 2; ++n)                         \
          acc[MH][NH][m][n] = __builtin_amdgcn_mfma_f32_16x16x32_fp8_fp8(     \
              af[m][kk], bf[n][kk], acc[MH][NH][m][n], 0, 0, 0);              \
    __builtin_amdgcn_s_setprio(0);                                            \
    if ((VM) == 1) asm volatile("s_waitcnt vmcnt(4)" ::: "memory");           \
    if ((VM) == 2) asm volatile("s_waitcnt vmcnt(0)" ::: "memory");           \
    __builtin_amdgcn_s_barrier();                                             \
  } while (0)

  // prologue: tiles 0 (buf0) and 1 (buf1) fully staged, drain once
  STG(0, 0, 0); STG(1, 0, 0); STG(0, 1, 0); STG(1, 1, 0);
  STG(0, 0, 1); STG(1, 0, 1); STG(0, 1, 1); STG(1, 1, 1);
  asm volatile("s_waitcnt vmcnt(0)" ::: "memory");
  __builtin_amdgcn_s_barrier();

  for (int t = 0; t < 4; ++t) {
    const int bsel = t & 1;
    const int stB = (t >= 1 && t < 3);      // stage B halves of t+1
    const int stA = (t < 2);                // stage A halves of t+2
    const int vm = (t < 2) ? 1 : (t == 2) ? 2 : 0;
    PHASE(0, 0, 1, 1, 0, if (stB) { STG(1, 0, t + 1); STG(1, 1, t + 1); });
    PHASE(0, 1, 0, 1, 0, if (stA) STG(0, 0, t + 2););
    PHASE(1, 1, 1, 0, 0, );
    PHASE(1, 0, 0, 1, vm, if (stA) STG(0, 1, t + 2););
  }
#undef PHASE

  // epilogue: store fp8 exp2 + f32 row partials.
  unsigned char* Pb = P + (size_t)bz * SS;
  float rp[2][4][4];
#pragma unroll
  for (int Mh = 0; Mh < 2; ++Mh)
#pragma unroll
    for (int m = 0; m < 4; ++m)
#pragma unroll
      for (int rr = 0; rr < 4; ++rr) {
        const int grow = bm * 256 + Mh * 128 + wrM * 64 + m * 16 + lhi * 4 + rr;
        float s = 0.f;
#pragma unroll
        for (int Nh = 0; Nh < 2; ++Nh)
#pragma unroll
          for (int n = 0; n < 2; ++n) {
            const int gcol = bn * 256 + Nh * 128 + wcN * 32 + n * 16 + llo;
            const float v = exp2f(acc[Mh][Nh][m][n][rr] * c);
            Pb[(size_t)grow * 4096 + gcol] = f2e4m3(v);
            s += v;
          }
        rp[Mh][m][rr] = s;
      }
#pragma unroll
  for (int Mh = 0; Mh < 2; ++Mh)
#pragma unroll
    for (int m = 0; m < 4; ++m)
#pragma unroll
      for (int rr = 0; rr < 4; ++rr) {
        float s = rp[Mh][m][rr];
        s += __shfl_xor(s, 1); s += __shfl_xor(s, 2);
        s += __shfl_xor(s, 4); s += __shfl_xor(s, 8);
        rp[Mh][m][rr] = s;
      }
  __syncthreads();
  float* rsl = (float*)sm;                  // [256][4]
  if (llo == 0) {
#pragma unroll
    for (int Mh = 0; Mh < 2; ++Mh)
#pragma unroll
      for (int m = 0; m < 4; ++m)
#pragma unroll
        for (int rr = 0; rr < 4; ++rr) {
          const int rl = Mh * 128 + wrM * 64 + m * 16 + lhi * 4 + rr;
          rsl[rl * 4 + wcN] = rp[Mh][m][rr];
        }
  }
  __syncthreads();
  if (tid < 256) {
    const float s = rsl[tid * 4] + rsl[tid * 4 + 1] + rsl[tid * 4 + 2] + rsl[tid * 4 + 3];
    part2[((size_t)bz * 16 + bn) * 4096 + bm * 256 + tid] = s;
  }
}

// rs[z][row] = 1 / sum_bn part2[z][bn][row].
__global__ __launch_bounds__(256)
void rs_final(const float* __restrict__ part2, float* __restrict__ rs)
{
  const int i = blockIdx.x * 256 + threadIdx.x;  // 0..8191
  const int z = i >> 12, row = i & 4095;
  float s = 0.f;
#pragma unroll
  for (int bn = 0; bn < 16; ++bn)
    s += part2[((size_t)z * 16 + bn) * 4096 + row];
  rs[(size_t)z * 4096 + row] = 1.f / s;
}

// ---------------------------------------------------------------------------
// pv_fp8: out[o][i] = (sum_j VO[o][j] P[i][j]) * rsum[i] + bvo[o] + x[o][i]
// VO fp8 [z][512][4096], P fp8 [z][4096][4096]. MF=2 tile 64x128, BK=128
// fp8 (128-B rows, same staging bytes as bf16 BK=64), nkt=32, 2-phase dbuf.
// SWZ=3 block map (512 blocks).
// ---------------------------------------------------------------------------
__global__ __launch_bounds__(256, 2)
void pv_fp8(const unsigned char* __restrict__ VOp,
            const unsigned char* __restrict__ P,
            float* __restrict__ out,
            const float* __restrict__ bvo,
            const float* __restrict__ x,
            const float* __restrict__ rsum)
{
  const long long VOz = 512LL * 4096;
  const long long SS  = 4096LL * 4096;
  const long long CHW = 512LL * 4096;

  const int b = blockIdx.x;                 // 512: 8m x 32n x 2z
  const int xcd = b & 7, slot = b >> 3;
  const int bm = slot & 7;
  const int panel = xcd * 8 + (slot >> 3);
  const int bn = panel & 31, bz = panel >> 5;

  const unsigned char* A = VOp + (size_t)bz * VOz;
  const unsigned char* B = P + (size_t)bz * SS;

  const int tid = threadIdx.x;
  const int w = tid >> 6, l = tid & 63;
  const int wr = w >> 1, wc = w & 1;
  const int lhi = l >> 4, llo = l & 15;
  const int m0 = bm * 64, n0 = bn * 128;

  constexpr int BUFSZ = 8192 + 16384;       // A 64x128B + B 128x128B
  __shared__ char sm[2 * BUFSZ];

  f32x4 acc[2][4] = {};

  const int rIn = l >> 3;
  const int colSw = 16 * ((l & 7) ^ (rIn & 7));

  const unsigned char* gAr[2];
  const unsigned char* gBr[4];
#pragma unroll
  for (int j = 0; j < 2; ++j)
    gAr[j] = A + (size_t)(m0 + w * 16 + j * 8 + rIn) * 4096 + colSw;
#pragma unroll
  for (int r = 0; r < 4; ++r)
    gBr[r] = B + (size_t)(n0 + w * 32 + r * 8 + rIn) * 4096 + colSw;

  auto stage = [&](int kt, int buf) {
    char* sA = sm + buf * BUFSZ;
    char* sB = sA + 8192;
    const int ko = kt * 128;
#pragma unroll
    for (int j = 0; j < 2; ++j)
      gload16(gAr[j] + ko, sA + (w * 2 + j) * 1024);
#pragma unroll
    for (int r = 0; r < 4; ++r)
      gload16(gBr[r] + ko, sB + (w * 4 + r) * 1024);
  };

  auto compute = [&](int buf) {
    char* sA = sm + buf * BUFSZ;
    char* sB = sA + 8192;
#pragma unroll
    for (int kk = 0; kk < 4; ++kk) {
      long long afv[2], bfv[4];
#pragma unroll
      for (int m = 0; m < 2; ++m) {
        const int row = wr * 32 + m * 16 + llo;
        afv[m] = *(const long long*)(sA + row * 128 +
            (((kk * 2 + (lhi >> 1)) ^ (row & 7)) * 16) + (lhi & 1) * 8);
      }
#pragma unroll
      for (int n = 0; n < 4; ++n) {
        const int row = wc * 64 + n * 16 + llo;
        bfv[n] = *(const long long*)(sB + row * 128 +
            (((kk * 2 + (lhi >> 1)) ^ (row & 7)) * 16) + (lhi & 1) * 8);
      }
#pragma unroll
      for (int m = 0; m < 2; ++m)
#pragma unroll
        for (int n = 0; n < 4; ++n)
          acc[m][n] = __builtin_amdgcn_mfma_f32_16x16x32_fp8_fp8(
              afv[m], bfv[n], acc[m][n], 0, 0, 0);
    }
  };

  const int nkt = 32;                       // 4096 / 128
  stage(0, 0);
  __syncthreads();
  int cur = 0;
  for (int kt = 0; kt < nkt; ++kt) {
    if (kt + 1 < nkt) stage(kt + 1, cur ^ 1);
    compute(cur);
    __syncthreads();
    cur ^= 1;
  }

#pragma unroll
  for (int m = 0; m < 2; ++m) {
#pragma unroll
    for (int r = 0; r < 4; ++r) {
      const int grow = m0 + wr * 32 + m * 16 + lhi * 4 + r;
#pragma unroll
      for (int n = 0; n < 4; ++n) {
        const int gcol = n0 + wc * 64 + n * 16 + llo;
        float v = acc[m][n][r] * rsum[(size_t)bz * 4096 + gcol] + bvo[grow];
        v += x[(size_t)bz * CHW + (size_t)grow * 4096 + gcol];
        out[(size_t)bz * CHW + (size_t)grow * 4096 + gcol] = v;
      }
    }
  }
}

// ---------------------------------------------------------------------------
// gemm_body: R5/R12-proven 4-wave bf16 NT GEMM core.
// OUTF: 0 bf16 out, 1 f32 out, 2 fp8 out. NORM 1: mul rn[z*4096+gcol].
// ---------------------------------------------------------------------------
template<int OUTF, int BIASMODE, int RESID, int PIPE, int MF, int NORM>
__device__ __forceinline__ void gemm_body(
    const __hip_bfloat16* __restrict__ A,
    const __hip_bfloat16* __restrict__ B,
    void* __restrict__ Cv,
    const float* __restrict__ bias,
    const float* __restrict__ resid,
    const float* __restrict__ rn,
    float scale, int K, int lda, int ldb, int ldc,
    long long strC, long long strR,
    int bm, int bn, int z, char* sm)
{
  constexpr int BUFSZ = MF * 4096 + 16384;
  const int tid = threadIdx.x;
  const int w = tid >> 6, l = tid & 63;
  const int wr = w >> 1, wc = w & 1;
  const int lhi = l >> 4, llo = l & 15;
  const int m0 = bm * (MF * 32), n0 = bn * 128;

  f32x4 acc[MF][4] = {};

  const int rowInCh = l >> 3;
  const int colOff = 8 * ((l & 7) ^ (rowInCh & 7));

  const __hip_bfloat16* gAr[MF];
  const __hip_bfloat16* gBr[4];
#pragma unroll
  for (int j = 0; j < MF; ++j)
    gAr[j] = A + (size_t)(m0 + w * (8 * MF) + j * 8 + rowInCh) * lda + colOff;
#pragma unroll
  for (int r = 0; r < 4; ++r)
    gBr[r] = B + (size_t)(n0 + w * 32 + r * 8 + rowInCh) * ldb + colOff;

  auto stage = [&](int kt, int buf) {
    char* sA = sm + buf * BUFSZ;
    char* sB = sA + MF * 4096;
    const int ko = kt * 64;
#pragma unroll
    for (int j = 0; j < MF; ++j)
      gload16(gAr[j] + ko, sA + (w * MF + j) * 1024);
#pragma unroll
    for (int r = 0; r < 4; ++r)
      gload16(gBr[r] + ko, sB + (w * 4 + r) * 1024);
  };

  auto compute = [&](int buf) {
    char* sA = sm + buf * BUFSZ;
    char* sB = sA + MF * 4096;
#pragma unroll
    for (int kk = 0; kk < 2; ++kk) {
      short8_t af[MF], bfv[4];
#pragma unroll
      for (int m = 0; m < MF; ++m) {
        const int row = wr * (16 * MF) + m * 16 + llo;
        const int inner = ((kk * 4 + lhi) ^ (row & 7)) * 16;
        af[m] = *(const short8_t*)(sA + row * 128 + inner);
      }
#pragma unroll
      for (int n = 0; n < 4; ++n) {
        const int row = wc * 64 + n * 16 + llo;
        const int inner = ((kk * 4 + lhi) ^ (row & 7)) * 16;
        bfv[n] = *(const short8_t*)(sB + row * 128 + inner);
      }
#pragma unroll
      for (int m = 0; m < MF; ++m)
#pragma unroll
        for (int n = 0; n < 4; ++n)
          acc[m][n] = __builtin_amdgcn_mfma_f32_16x16x32_bf16(af[m], bfv[n], acc[m][n], 0, 0, 0);
    }
  };

  const int nkt = K >> 6;
  if (PIPE) {
    stage(0, 0);
    __syncthreads();
    int cur = 0;
    for (int kt = 0; kt < nkt; ++kt) {
      if (kt + 1 < nkt) stage(kt + 1, cur ^ 1);
      compute(cur);
      __syncthreads();
      cur ^= 1;
    }
  } else {
    for (int kt = 0; kt < nkt; ++kt) {
      __syncthreads();
      stage(kt, 0);
      __syncthreads();
      compute(0);
    }
  }

#pragma unroll
  for (int m = 0; m < MF; ++m) {
#pragma unroll
    for (int r = 0; r < 4; ++r) {
      const int grow = m0 + wr * (16 * MF) + m * 16 + lhi * 4 + r;
#pragma unroll
      for (int n = 0; n < 4; ++n) {
        const int gcol = n0 + wc * 64 + n * 16 + llo;
        float v = acc[m][n][r] * scale;
        if (NORM == 1) v *= rn[(size_t)z * 4096 + gcol];
        if (BIASMODE == 1) v += bias[grow];
        if (BIASMODE == 2) v += bias[gcol];
        const size_t idx = (size_t)z * strC + (size_t)grow * ldc + gcol;
        if (RESID) v += resid[(size_t)z * strR + (size_t)grow * ldc + gcol];
        if (OUTF == 0)      ((__hip_bfloat16*)Cv)[idx] = __float2bfloat16(v);
        else if (OUTF == 1) ((float*)Cv)[idx] = v;
        else                ((unsigned char*)Cv)[idx] = f2e4m3(v);
      }
    }
  }
}

template<int OUTF, int BIASMODE, int RESID, int PIPE, int SWZ, int MF, int NORM>
__global__ __launch_bounds__(256, 2)
void gemm_nt(const __hip_bfloat16* __restrict__ A,
             const __hip_bfloat16* __restrict__ B,
             void* __restrict__ Cv,
             const float* __restrict__ bias,
             const float* __restrict__ resid,
             const float* __restrict__ rn,
             float scale, int M, int N, int K,
             int lda, int ldb, int ldc,
             long long strA, long long strB, long long strC, long long strR)
{
  int bm, bn, bz;
  if (SWZ == 0) {
    bm = blockIdx.x; bn = blockIdx.y; bz = blockIdx.z;
  } else {
    const int b = blockIdx.x;                 // 512 blocks (8m x 32n x 2z)
    const int xcd = b & 7, slot = b >> 3;
    bm = slot & 7;
    const int panel = xcd * 8 + (slot >> 3);
    bn = panel & 31; bz = panel >> 5;
  }
  __shared__ char sm[(PIPE ? 2 : 1) * (MF * 4096 + 16384)];
  gemm_body<OUTF, BIASMODE, RESID, PIPE, MF, NORM>(
      A + (size_t)bz * strA, B + (size_t)bz * strB, Cv, bias, resid, rn,
      scale, K, lda, ldb, ldc, strC, strR, bm, bn, bz, sm);
}

// ---------------------------------------------------------------------------
// qkvo: QK (blocks 0..511, fp8 out) + VO (512..1023, fp8 out), bf16 MFMA.
// ---------------------------------------------------------------------------
__global__ __launch_bounds__(256, 2)
void qkvo(const __hip_bfloat16* __restrict__ ht,
          const __hip_bfloat16* __restrict__ wqk,
          const __hip_bfloat16* __restrict__ wvo,
          unsigned char* __restrict__ qk8,
          unsigned char* __restrict__ vo8,
          const float* __restrict__ bqk)
{
  const long long HT  = 4096LL * 512;
  const long long QKz = 4096LL * 1024;
  const long long VOz = 512LL * 4096;
  __shared__ char sm[65536];
  const int b = blockIdx.x;
  if (b < 512) {
    const int bm = b & 31, bn = (b >> 5) & 7, bz = b >> 8;
    gemm_body<2, 2, 0, 1, 4, 0>(
        ht + (size_t)bz * HT, wqk, qk8, bqk, nullptr, nullptr,
        1.f, 512, 512, 512, 1024, QKz, 0, bm, bn, bz, sm);
  } else {
    const int b2 = b - 512;
    const int xcd = b2 & 7, slot = b2 >> 3;
    const int bm = slot & 7;
    const int panel = xcd * 8 + (slot >> 3);
    const int bn = panel & 31, bz = panel >> 5;
    gemm_body<2, 0, 0, 1, 2, 0>(
        wvo, ht + (size_t)bz * HT, vo8, nullptr, nullptr, nullptr,
        1.f, 512, 512, 512, 4096, VOz, 0, bm, bn, bz, sm);
  }
}

// ---------------------------------------------------------------------------
// prep_all: segmented grid (1858 blocks x 256 thr).
// ---------------------------------------------------------------------------
__global__ __launch_bounds__(256)
void prep_all(const float* __restrict__ wq, const float* __restrict__ wk,
              const float* __restrict__ wo, const float* __restrict__ wv,
              const float* __restrict__ bv, const float* __restrict__ bo,
              const float* __restrict__ bq, const float* __restrict__ bk,
              const float* __restrict__ x,
              __hip_bfloat16* __restrict__ wbf, __hip_bfloat16* __restrict__ wvT,
              float* __restrict__ bvo, float* __restrict__ bqk,
              float* __restrict__ part)
{
  const int b = blockIdx.x, tid = threadIdx.x;
  if (b < 768) {
    const int j = b >> 8;
    const float* src = (j == 0) ? wq : (j == 1) ? wk : wo;
    const int i = (b & 255) * 256 + tid;
    float4 v = reinterpret_cast<const float4*>(src)[i];
    short4_t o;
    o[0] = f2bf_bits(v.x); o[1] = f2bf_bits(v.y);
    o[2] = f2bf_bits(v.z); o[3] = f2bf_bits(v.w);
    *reinterpret_cast<short4_t*>((short*)wbf + (size_t)j * 262144 + (size_t)i * 4) = o;
  } else if (b < 832) {
    __shared__ float tile[64][65];
    const int b2 = b - 768, ct = b2 >> 3, it = b2 & 7;
    const int lane = tid & 63, rr = tid >> 6;
#pragma unroll
    for (int p = 0; p < 16; ++p) {
      const int cl = p * 4 + rr;
      tile[cl][lane] = wv[(size_t)(ct * 64 + cl) * 512 + it * 64 + lane];
    }
    __syncthreads();
#pragma unroll
    for (int p = 0; p < 16; ++p) {
      const int il = p * 4 + rr;
      wvT[(size_t)(it * 64 + il) * 512 + ct * 64 + lane] = __float2bfloat16(tile[lane][il]);
    }
  } else if (b < 834) {
    const int o = (b - 832) * 256 + tid;
    const float4* row = reinterpret_cast<const float4*>(wo + (size_t)o * 512);
    const float4* b4 = reinterpret_cast<const float4*>(bv);
    float s = 0.f;
#pragma unroll 8
    for (int i = 0; i < 128; ++i) {
      float4 a = row[i], bb = b4[i];
      s += a.x * bb.x + a.y * bb.y + a.z * bb.z + a.w * bb.w;
    }
    bvo[o] = s + bo[o];
    bqk[o] = bq[o];
    bqk[512 + o] = bk[o];
  } else {
    const int b3 = b - 834;
    const int g = b3 & 31, sl = (b3 >> 5) & 15, z = b3 >> 9;
    const float* xf = x + (size_t)z * 512 * 4096 + (size_t)g * 16 * 4096 + (size_t)sl * 4096;
    const float4* px = reinterpret_cast<const float4*>(xf);
    float s = 0.f, q = 0.f;
#pragma unroll
    for (int i = 0; i < 4; ++i) {
      float4 v = px[tid + i * 256];
      s += v.x + v.y + v.z + v.w;
      q += v.x * v.x + v.y * v.y + v.z * v.z + v.w * v.w;
    }
#pragma unroll
    for (int o = 32; o; o >>= 1) { s += __shfl_xor(s, o); q += __shfl_xor(q, o); }
    __shared__ float rs[4], rq[4];
    if ((tid & 63) == 0) { rs[tid >> 6] = s; rq[tid >> 6] = q; }
    __syncthreads();
    if (tid == 0) {
      s = rs[0] + rs[1] + rs[2] + rs[3];
      q = rq[0] + rq[1] + rq[2] + rq[3];
      part[(((size_t)z * 32 + g) * 16 + sl) * 2 + 0] = s;
      part[(((size_t)z * 32 + g) * 16 + sl) * 2 + 1] = q;
    }
  }
}

// ---------------------------------------------------------------------------
__global__ __launch_bounds__(256)
void gn_apply_t(const float* __restrict__ x, const float* __restrict__ part,
                const float* __restrict__ gns, const float* __restrict__ gnb,
                __hip_bfloat16* __restrict__ ht)
{
  const int st = blockIdx.x, ct = blockIdx.y, z = blockIdx.z;
  const int tid = threadIdx.x;
  __shared__ float tile[64][65];
  __shared__ float smean[4], srstd[4];
  if (tid < 4) {
    const int g = ct * 4 + tid;
    float s = 0.f, q = 0.f;
#pragma unroll
    for (int slc = 0; slc < 16; ++slc) {
      s += part[(((size_t)z * 32 + g) * 16 + slc) * 2 + 0];
      q += part[(((size_t)z * 32 + g) * 16 + slc) * 2 + 1];
    }
    const float mean = s * (1.0f / 65536.0f);
    const float var = q * (1.0f / 65536.0f) - mean * mean;
    smean[tid] = mean;
    srstd[tid] = rsqrtf(var + 1e-6f);
  }
  __syncthreads();
  const float* xb = x + (size_t)z * 512 * 4096;
  const int lane64 = tid & 63, rr = tid >> 6;
#pragma unroll
  for (int pp = 0; pp < 16; ++pp) {
    const int cl = pp * 4 + rr;
    const int c = ct * 64 + cl;
    const float val = xb[(size_t)c * 4096 + st * 64 + lane64];
    tile[cl][lane64] = (val - smean[cl >> 4]) * srstd[cl >> 4] * gns[c] + gnb[c];
  }
  __syncthreads();
  __hip_bfloat16* hb = ht + (size_t)z * 4096 * 512;
#pragma unroll
  for (int pp = 0; pp < 16; ++pp) {
    const int sl = pp * 4 + rr;
    const int s = st * 64 + sl;
    hb[(size_t)s * 512 + ct * 64 + lane64] = __float2bfloat16(tile[lane64][sl]);
  }
}

// ---------------------------------------------------------------------------
// MODE1 fallback softmax (bf16 path).
// ---------------------------------------------------------------------------
__global__ __launch_bounds__(256)
void softmax_rows(__hip_bfloat16* __restrict__ S, long long strZ)
{
  const int row = blockIdx.x, z = blockIdx.y;
  __hip_bfloat16* p = S + (size_t)z * strZ + (size_t)row * 4096;
  const int tid = threadIdx.x;
  short8_t a = *(const short8_t*)(p + tid * 16);
  short8_t b = *(const short8_t*)(p + tid * 16 + 8);
  float v[16];
#pragma unroll
  for (int i = 0; i < 8; ++i) { v[i] = bfbits2f(a[i]); v[8 + i] = bfbits2f(b[i]); }
  float m = v[0];
#pragma unroll
  for (int i = 1; i < 16; ++i) m = fmaxf(m, v[i]);
#pragma unroll
  for (int o = 32; o; o >>= 1) m = fmaxf(m, __shfl_xor(m, o));
  __shared__ float red[8];
  if ((tid & 63) == 0) red[tid >> 6] = m;
  __syncthreads();
  m = fmaxf(fmaxf(red[0], red[1]), fmaxf(red[2], red[3]));
  float s = 0.f;
#pragma unroll
  for (int i = 0; i < 16; ++i) { v[i] = exp2f((v[i] - m) * 1.44269504f); s += v[i]; }
#pragma unroll
  for (int o = 32; o; o >>= 1) s += __shfl_xor(s, o);
  __syncthreads();
  if ((tid & 63) == 0) red[4 + (tid >> 6)] = s;
  __syncthreads();
  s = red[4] + red[5] + red[6] + red[7];
  const float inv = 1.f / s;
#pragma unroll
  for (int i = 0; i < 8; ++i) { a[i] = f2bf_bits(v[i] * inv); b[i] = f2bf_bits(v[8 + i] * inv); }
  *(short8_t*)(p + tid * 16) = a;
  *(short8_t*)(p + tid * 16 + 8) = b;
}

// ---------------------------------------------------------------------------
extern "C" void kernel_launch(void* const* d_in, const int* in_sizes, int n_in,
                              void* d_out, int out_size, void* d_ws, size_t ws_size,
                              hipStream_t stream)
{
  const float* x   = (const float*)d_in[0];
  const float* gns = (const float*)d_in[1];
  const float* gnb = (const float*)d_in[2];
  const float* wq  = (const float*)d_in[3];
  const float* bq  = (const float*)d_in[4];
  const float* wk  = (const float*)d_in[5];
  const float* bk  = (const float*)d_in[6];
  const float* wv  = (const float*)d_in[7];
  const float* bv  = (const float*)d_in[8];
  const float* wo  = (const float*)d_in[9];
  const float* bo  = (const float*)d_in[10];
  float* out = (float*)d_out;

  const int WB = 512 * 512;
  const long long HT  = 4096LL * 512;
  const long long QKz = 4096LL * 1024;
  const long long VOz = 512LL * 4096;
  const long long SS  = 4096LL * 4096;
  const long long CHW = 512LL * 4096;

  char* base = (char*)d_ws;
  size_t off = 0;
  auto alloc = [&](size_t b) { void* r = base + off; off = (off + b + 255) & ~(size_t)255; return r; };

  __hip_bfloat16* wbf = (__hip_bfloat16*)alloc((size_t)5 * WB * 2);
  float* bqk   = (float*)alloc(1024 * 4);
  float* bvo   = (float*)alloc(512 * 4);
  float* part  = (float*)alloc(2 * 32 * 16 * 2 * 4);
  float* rsum  = (float*)alloc(2 * 4096 * 4);
  float* part2 = (float*)alloc((size_t)2 * 16 * 4096 * 4);
  const size_t fixed = off;

  // MODE2 (fp8): qk 8MB + vo 4MB + P 32MB. MODE1 (bf16): 16 + 8 + 32 MB.
  const int MODE = (ws_size >= fixed + (size_t)2 * QKz + (size_t)2 * VOz +
                    (size_t)2 * SS + (size_t)4 * HT) ? 2 : 1;

  __hip_bfloat16* wqk = wbf;
  __hip_bfloat16* woB = wbf + 2 * WB;
  __hip_bfloat16* wvT = wbf + 3 * WB;
  __hip_bfloat16* wvo = wbf + 4 * WB;

  const float SC = 0.04419417382415922f;                 // 512^-0.5
  const float CEXP = SC * 1.4426950408889634f;

  prep_all<<<1858, 256, 0, stream>>>(wq, wk, wo, wv, bv, bo, bq, bk, x,
                                     wbf, wvT, bvo, bqk, part);

  // WVO[o][i] = sum_c wo[o][c] * wvT[i][c]   (bf16 out)
  gemm_nt<0, 0, 0, 1, 0, 4, 0><<<dim3(4, 4, 1), 256, 0, stream>>>(
      woB, wvT, wvo, nullptr, nullptr, nullptr, 1.f, 512, 512, 512,
      512, 512, 512, 0, 0, 0, 0);

  if (MODE == 2) {
    unsigned char* qk8  = (unsigned char*)alloc((size_t)2 * QKz);
    unsigned char* vo8  = (unsigned char*)alloc((size_t)2 * VOz);
    unsigned char* p8   = (unsigned char*)alloc((size_t)2 * SS);
    // ht aliases the tail of p8 (dead before s_gemm8f writes P).
    __hip_bfloat16* ht = (__hip_bfloat16*)(p8 + (size_t)2 * SS - (size_t)4 * HT);

    gn_apply_t<<<dim3(64, 8, 2), 256, 0, stream>>>(x, part, gns, gnb, ht);
    qkvo<<<1024, 256, 0, stream>>>(ht, wqk, wvo, qk8, vo8, bqk);
    s_gemm8f<<<512, 512, 0, stream>>>(qk8, p8, part2, CEXP);
    rs_final<<<32, 256, 0, stream>>>(part2, rsum);
    pv_fp8<<<512, 256, 0, stream>>>(vo8, p8, out, bvo, x, rsum);
  } else {
    __hip_bfloat16* qk   = (__hip_bfloat16*)alloc((size_t)2 * QKz * 2);
    __hip_bfloat16* vo   = (__hip_bfloat16*)alloc((size_t)2 * VOz * 2);
    __hip_bfloat16* sbuf = (__hip_bfloat16*)alloc((size_t)SS * 2);
    __hip_bfloat16* ht   = (__hip_bfloat16*)((char*)sbuf + (size_t)SS * 2 - (size_t)4 * HT);

    gn_apply_t<<<dim3(64, 8, 2), 256, 0, stream>>>(x, part, gns, gnb, ht);
    gemm_nt<0, 2, 0, 1, 0, 4, 0><<<dim3(32, 8, 2), 256, 0, stream>>>(
        ht, wqk, qk, bqk, nullptr, nullptr, 1.f, 4096, 1024, 512,
        512, 512, 1024, HT, 0, QKz, 0);
    gemm_nt<0, 0, 0, 1, 3, 2, 0><<<dim3(512, 1, 1), 256, 0, stream>>>(
        wvo, ht, vo, nullptr, nullptr, nullptr, 1.f, 512, 4096, 512,
        512, 512, 4096, 0, HT, VOz, 0);
    for (int z = 0; z < 2; ++z) {
      gemm_nt<0, 0, 0, 0, 0, 4, 0><<<dim3(32, 32, 1), 256, 0, stream>>>(
          qk + (size_t)z * QKz, qk + (size_t)z * QKz + 512, sbuf, nullptr, nullptr,
          nullptr, SC, 4096, 4096, 512, 1024, 1024, 4096, 0, 0, 0, 0);
      softmax_rows<<<dim3(4096, 1), 256, 0, stream>>>(sbuf, 0);
      gemm_nt<1, 1, 1, 1, 0, 2, 0><<<dim3(8, 32, 1), 256, 0, stream>>>(
          vo + (size_t)z * VOz, sbuf, out + (size_t)z * CHW, bvo, x + (size_t)z * CHW,
          nullptr, 1.f, 512, 4096, 4096, 4096, 4096, 4096, 0, 0, 0, 0);
    }
  }
}

// Round 16
// 145.455 us; speedup vs baseline: 1.2724x; 1.2724x over previous
//
#include <hip/hip_runtime.h>
#include <hip/hip_bf16.h>

// AttnBlock: GN -> QKV 1x1conv -> attention(n=4096,d=512) -> out-proj -> +x
// R16 = R14 (proven best, 145.7us). R15's fp8 attempt regressed: fp8 b64
// fragment reads have a structural LDS half-slot conflict (3.5M conflicts)
// that global_load_lds pre-swizzle cannot fix (16B pair granularity).
// Final structure: prep_all + WVO fold (V/out-proj GEMMs eliminated) +
// inline-stats GN transpose + merged qkvo + s_gemm8 (exp fused, softmax
// eliminated) + rs_final + PV with rsum/bias/residual epilogue.

typedef __attribute__((ext_vector_type(8))) short short8_t;
typedef __attribute__((ext_vector_type(4))) short short4_t;
typedef __attribute__((ext_vector_type(4))) float f32x4;

__device__ __forceinline__ void gload16(const void* g, void* l) {
  __builtin_amdgcn_global_load_lds(
      (const __attribute__((address_space(1))) void*)g,
      (__attribute__((address_space(3))) void*)l, 16, 0, 0);
}

__device__ __forceinline__ short f2bf_bits(float f) {
  __hip_bfloat16 h = __float2bfloat16(f);
  return *reinterpret_cast<short*>(&h);
}
__device__ __forceinline__ float bfbits2f(short s) {
  union { unsigned int u; float f; } c;
  c.u = ((unsigned int)(unsigned short)s) << 16;
  return c.f;
}

// ---------------------------------------------------------------------------
// s_gemm8: Punnorm[i][j] = exp2(c * Q[i][:].K[j][:]) + per-(bn) row partials.
// ---------------------------------------------------------------------------
__global__ __launch_bounds__(512)
void s_gemm8(const __hip_bfloat16* __restrict__ qk,
             __hip_bfloat16* __restrict__ P, float* __restrict__ part2,
             float c)
{
  const long long QKz = 4096LL * 1024;
  const long long SS  = 4096LL * 4096;

  const int b = blockIdx.x;                 // 512 blocks: 16m x 16n x 2z
  const int bz = b >> 8;
  const int r = b & 255, xcd = r & 7, sl = r >> 3;
  const int bm = (xcd >> 1) * 4 + (sl & 3);
  const int bn = (xcd & 1) * 8 + (sl >> 2);

  const __hip_bfloat16* Aq = qk + (size_t)bz * QKz;
  const __hip_bfloat16* Bk = Aq + 512;

  const int tid = threadIdx.x;
  const int wid = tid >> 6, l = tid & 63;
  const int wrM = wid >> 2, wcN = wid & 3;
  const int lhi = l >> 4, llo = l & 15;

  __shared__ char sm[2 * 65536];            // [buf][A 32KB | B 32KB]

  f32x4 acc[2][2][4][2] = {};               // [Mh][Nh][m][n]
  short8_t af[4][2], bf[2][2];              // persistent fragments

  const int rIn = l >> 3;
  const int colSw = 8 * ((l & 7) ^ (rIn & 7));
  const __hip_bfloat16* gA = Aq + (size_t)(bm * 256 + rIn) * 1024 + colSw;
  const __hip_bfloat16* gB = Bk + (size_t)(bn * 256 + rIn) * 1024 + colSw;

  auto STG = [&](int mat, int half, int t) {
    const __hip_bfloat16* src = mat ? gB : gA;
    char* dst = sm + (t & 1) * 65536 + mat * 32768;
    const int rb = half * 128 + wid * 16;
    gload16(src + (size_t)rb * 1024 + t * 64, dst + rb * 128);
    gload16(src + (size_t)(rb + 8) * 1024 + t * 64, dst + (rb + 8) * 128);
  };

#define PHASE(MH, NH, LA, LB, VM, ...) do {                                   \
    const char* bbA = sm + bsel * 65536;                                      \
    const char* bbB = bbA + 32768;                                            \
    if (LA) {                                                                 \
      _Pragma("unroll") for (int m = 0; m < 4; ++m) {                         \
        const int rowA = (MH) * 128 + wrM * 64 + m * 16 + llo;                \
        _Pragma("unroll") for (int kk = 0; kk < 2; ++kk)                      \
          af[m][kk] = *(const short8_t*)(bbA + rowA * 128 +                   \
                        (((kk * 4 + lhi) ^ (rowA & 7)) * 16));                \
      }                                                                       \
    }                                                                         \
    if (LB) {                                                                 \
      _Pragma("unroll") for (int n = 0; n < 2; ++n) {                         \
        const int rowB = (NH) * 128 + wcN * 32 + n * 16 + llo;                \
        _Pragma("unroll") for (int kk = 0; kk < 2; ++kk)                      \
          bf[n][kk] = *(const short8_t*)(bbB + rowB * 128 +                   \
                        (((kk * 4 + lhi) ^ (rowB & 7)) * 16));                \
      }                                                                       \
    }                                                                         \
    __VA_ARGS__;                                                              \
    __builtin_amdgcn_s_barrier();                                             \
    __builtin_amdgcn_s_setprio(1);                                            \
    _Pragma("unroll") for (int kk = 0; kk < 2; ++kk)                          \
      _Pragma("unroll") for (int m = 0; m < 4; ++m)                           \
        _Pragma("unroll") for (int n = 0; n < 2; ++n)                         \
          acc[MH][NH][m][n] = __builtin_amdgcn_mfma_f32_16x16x32_bf16(        \
              af[m][kk], bf[n][kk], acc[MH][NH][m][n], 0, 0, 0);              \
    __builtin_amdgcn_s_setprio(0);                                            \
    if ((VM) == 1) asm volatile("s_waitcnt vmcnt(4)" ::: "memory");           \
    if ((VM) == 2) asm volatile("s_waitcnt vmcnt(0)" ::: "memory");           \
    __builtin_amdgcn_s_barrier();                                             \
  } while (0)

  // prologue: tiles 0 (buf0) and 1 (buf1) fully staged, then drain once
  STG(0, 0, 0); STG(1, 0, 0); STG(0, 1, 0); STG(1, 1, 0);
  STG(0, 0, 1); STG(1, 0, 1); STG(0, 1, 1); STG(1, 1, 1);
  asm volatile("s_waitcnt vmcnt(0)" ::: "memory");
  __builtin_amdgcn_s_barrier();

  for (int t = 0; t < 8; ++t) {
    const int bsel = t & 1;
    const int stB = (t >= 1 && t < 7);      // stage B halves of t+1
    const int stA = (t < 6);                // stage A halves of t+2
    const int vm = (t < 6) ? 1 : (t == 6) ? 2 : 0;
    PHASE(0, 0, 1, 1, 0, if (stB) { STG(1, 0, t + 1); STG(1, 1, t + 1); });
    PHASE(0, 1, 0, 1, 0, if (stA) STG(0, 0, t + 2););
    PHASE(1, 1, 1, 0, 0, );
    PHASE(1, 0, 0, 1, vm, if (stA) STG(0, 1, t + 2););
  }
#undef PHASE

  // epilogue: store exp2 + row partials. C/D: col=lane&15, row=(lane>>4)*4+reg
  __hip_bfloat16* Pb = P + (size_t)bz * SS;
  float rp[2][4][4];                        // [Mh][m][rr] per-lane row partial
#pragma unroll
  for (int Mh = 0; Mh < 2; ++Mh)
#pragma unroll
    for (int m = 0; m < 4; ++m)
#pragma unroll
      for (int rr = 0; rr < 4; ++rr) {
        const int grow = bm * 256 + Mh * 128 + wrM * 64 + m * 16 + lhi * 4 + rr;
        float s = 0.f;
#pragma unroll
        for (int Nh = 0; Nh < 2; ++Nh)
#pragma unroll
          for (int n = 0; n < 2; ++n) {
            const int gcol = bn * 256 + Nh * 128 + wcN * 32 + n * 16 + llo;
            const float v = exp2f(acc[Mh][Nh][m][n][rr] * c);
            Pb[(size_t)grow * 4096 + gcol] = __float2bfloat16(v);
            s += v;
          }
        rp[Mh][m][rr] = s;
      }
#pragma unroll
  for (int Mh = 0; Mh < 2; ++Mh)
#pragma unroll
    for (int m = 0; m < 4; ++m)
#pragma unroll
      for (int rr = 0; rr < 4; ++rr) {
        float s = rp[Mh][m][rr];
        s += __shfl_xor(s, 1); s += __shfl_xor(s, 2);
        s += __shfl_xor(s, 4); s += __shfl_xor(s, 8);
        rp[Mh][m][rr] = s;
      }
  __syncthreads();                          // safe to reuse sm
  float* rsl = (float*)sm;                  // [256][4]
  if (llo == 0) {
#pragma unroll
    for (int Mh = 0; Mh < 2; ++Mh)
#pragma unroll
      for (int m = 0; m < 4; ++m)
#pragma unroll
        for (int rr = 0; rr < 4; ++rr) {
          const int rl = Mh * 128 + wrM * 64 + m * 16 + lhi * 4 + rr;
          rsl[rl * 4 + wcN] = rp[Mh][m][rr];
        }
  }
  __syncthreads();
  if (tid < 256) {
    const float s = rsl[tid * 4] + rsl[tid * 4 + 1] + rsl[tid * 4 + 2] + rsl[tid * 4 + 3];
    part2[((size_t)bz * 16 + bn) * 4096 + bm * 256 + tid] = s;
  }
}

// rs[z][row] = 1 / sum_bn part2[z][bn][row].  8192 threads.
__global__ __launch_bounds__(256)
void rs_final(const float* __restrict__ part2, float* __restrict__ rs)
{
  const int i = blockIdx.x * 256 + threadIdx.x;  // 0..8191
  const int z = i >> 12, row = i & 4095;
  float s = 0.f;
#pragma unroll
  for (int bn = 0; bn < 16; ++bn)
    s += part2[((size_t)z * 16 + bn) * 4096 + row];
  rs[(size_t)z * 4096 + row] = 1.f / s;
}

// ---------------------------------------------------------------------------
// gemm_body: R5/R12-proven 4-wave NT GEMM core as a device function.
// NORM: 0 none; 1 = multiply by rn[z*4096+gcol] (precomputed 1/rowsum).
// ---------------------------------------------------------------------------
template<int OUTF, int BIASMODE, int RESID, int PIPE, int MF, int NORM>
__device__ __forceinline__ void gemm_body(
    const __hip_bfloat16* __restrict__ A,   // already z-offset
    const __hip_bfloat16* __restrict__ B,   // already z-offset
    void* __restrict__ Cv,
    const float* __restrict__ bias,
    const float* __restrict__ resid,
    const float* __restrict__ rn,
    float scale, int K, int lda, int ldb, int ldc,
    long long strC, long long strR,
    int bm, int bn, int z, char* sm)
{
  constexpr int BUFSZ = MF * 4096 + 16384;
  const int tid = threadIdx.x;
  const int w = tid >> 6, l = tid & 63;
  const int wr = w >> 1, wc = w & 1;
  const int lhi = l >> 4, llo = l & 15;
  const int m0 = bm * (MF * 32), n0 = bn * 128;

  f32x4 acc[MF][4] = {};

  const int rowInCh = l >> 3;
  const int colOff = 8 * ((l & 7) ^ (rowInCh & 7));

  const __hip_bfloat16* gAr[MF];
  const __hip_bfloat16* gBr[4];
#pragma unroll
  for (int j = 0; j < MF; ++j)
    gAr[j] = A + (size_t)(m0 + w * (8 * MF) + j * 8 + rowInCh) * lda + colOff;
#pragma unroll
  for (int r = 0; r < 4; ++r)
    gBr[r] = B + (size_t)(n0 + w * 32 + r * 8 + rowInCh) * ldb + colOff;

  auto stage = [&](int kt, int buf) {
    char* sA = sm + buf * BUFSZ;
    char* sB = sA + MF * 4096;
    const int ko = kt * 64;
#pragma unroll
    for (int j = 0; j < MF; ++j)
      gload16(gAr[j] + ko, sA + (w * MF + j) * 1024);
#pragma unroll
    for (int r = 0; r < 4; ++r)
      gload16(gBr[r] + ko, sB + (w * 4 + r) * 1024);
  };

  auto compute = [&](int buf) {
    char* sA = sm + buf * BUFSZ;
    char* sB = sA + MF * 4096;
#pragma unroll
    for (int kk = 0; kk < 2; ++kk) {
      short8_t af[MF], bfv[4];
#pragma unroll
      for (int m = 0; m < MF; ++m) {
        const int row = wr * (16 * MF) + m * 16 + llo;
        const int inner = ((kk * 4 + lhi) ^ (row & 7)) * 16;
        af[m] = *(const short8_t*)(sA + row * 128 + inner);
      }
#pragma unroll
      for (int n = 0; n < 4; ++n) {
        const int row = wc * 64 + n * 16 + llo;
        const int inner = ((kk * 4 + lhi) ^ (row & 7)) * 16;
        bfv[n] = *(const short8_t*)(sB + row * 128 + inner);
      }
#pragma unroll
      for (int m = 0; m < MF; ++m)
#pragma unroll
        for (int n = 0; n < 4; ++n)
          acc[m][n] = __builtin_amdgcn_mfma_f32_16x16x32_bf16(af[m], bfv[n], acc[m][n], 0, 0, 0);
    }
  };

  const int nkt = K >> 6;
  if (PIPE) {
    stage(0, 0);
    __syncthreads();
    int cur = 0;
    for (int kt = 0; kt < nkt; ++kt) {
      if (kt + 1 < nkt) stage(kt + 1, cur ^ 1);
      compute(cur);
      __syncthreads();
      cur ^= 1;
    }
  } else {
    for (int kt = 0; kt < nkt; ++kt) {
      __syncthreads();
      stage(kt, 0);
      __syncthreads();
      compute(0);
    }
  }

#pragma unroll
  for (int m = 0; m < MF; ++m) {
#pragma unroll
    for (int r = 0; r < 4; ++r) {
      const int grow = m0 + wr * (16 * MF) + m * 16 + lhi * 4 + r;
#pragma unroll
      for (int n = 0; n < 4; ++n) {
        const int gcol = n0 + wc * 64 + n * 16 + llo;
        float v = acc[m][n][r] * scale;
        if (NORM == 1) v *= rn[(size_t)z * 4096 + gcol];
        if (BIASMODE == 1) v += bias[grow];
        if (BIASMODE == 2) v += bias[gcol];
        const size_t idx = (size_t)z * strC + (size_t)grow * ldc + gcol;
        if (RESID) v += resid[(size_t)z * strR + (size_t)grow * ldc + gcol];
        if (OUTF == 0) ((__hip_bfloat16*)Cv)[idx] = __float2bfloat16(v);
        else           ((float*)Cv)[idx] = v;
      }
    }
  }
}

// Global wrapper with SWZ block maps (WVO, MODE1 paths, MODE2 PV).
template<int OUTF, int BIASMODE, int RESID, int PIPE, int SWZ, int MF, int NORM>
__global__ __launch_bounds__(256, 2)
void gemm_nt(const __hip_bfloat16* __restrict__ A,
             const __hip_bfloat16* __restrict__ B,
             void* __restrict__ Cv,
             const float* __restrict__ bias,
             const float* __restrict__ resid,
             const float* __restrict__ rn,
             float scale, int M, int N, int K,
             int lda, int ldb, int ldc,
             long long strA, long long strB, long long strC, long long strR)
{
  int bm, bn, bz;
  if (SWZ == 0) {
    bm = blockIdx.x; bn = blockIdx.y; bz = blockIdx.z;
  } else if (SWZ == 2) {
    const int b = blockIdx.x;            // 2048 blocks
    bz = b >> 10;
    const int b2 = b & 1023;
    const int xcd = b2 & 7, s = b2 >> 3;
    bm = (xcd >> 1) * 8 + (s & 7);
    bn = (xcd & 1) * 16 + (s >> 3);
  } else {
    const int b = blockIdx.x;                 // 512 blocks (8m x 32n x 2z)
    const int xcd = b & 7, slot = b >> 3;
    bm = slot & 7;
    const int panel = xcd * 8 + (slot >> 3);
    bn = panel & 31; bz = panel >> 5;
  }
  __shared__ char sm[(PIPE ? 2 : 1) * (MF * 4096 + 16384)];
  gemm_body<OUTF, BIASMODE, RESID, PIPE, MF, NORM>(
      A + (size_t)bz * strA, B + (size_t)bz * strB, Cv, bias, resid, rn,
      scale, K, lda, ldb, ldc, strC, strR, bm, bn, bz, sm);
}

// ---------------------------------------------------------------------------
// qkvo: QK (blocks 0..511) + VO (blocks 512..1023) in one dispatch.
// ---------------------------------------------------------------------------
__global__ __launch_bounds__(256, 2)
void qkvo(const __hip_bfloat16* __restrict__ ht,
          const __hip_bfloat16* __restrict__ wqk,
          const __hip_bfloat16* __restrict__ wvo,
          __hip_bfloat16* __restrict__ qk,
          __hip_bfloat16* __restrict__ vo,
          const float* __restrict__ bqk)
{
  const long long HT  = 4096LL * 512;
  const long long QKz = 4096LL * 1024;
  const long long VOz = 512LL * 4096;
  __shared__ char sm[65536];                 // max(QK 64KB, VO 48KB)
  const int b = blockIdx.x;
  if (b < 512) {
    // QK: [Q|K][s][o2] = ht . wqk^T + bqk
    const int bm = b & 31, bn = (b >> 5) & 7, bz = b >> 8;
    gemm_body<0, 2, 0, 1, 4, 0>(
        ht + (size_t)bz * HT, wqk, qk, bqk, nullptr, nullptr,
        1.f, 512, 512, 512, 1024, QKz, 0, bm, bn, bz, sm);
  } else {
    // VO: VO[o][j] = WVO . ht^T   (SWZ=3 map on b-512)
    const int b2 = b - 512;
    const int xcd = b2 & 7, slot = b2 >> 3;
    const int bm = slot & 7;
    const int panel = xcd * 8 + (slot >> 3);
    const int bn = panel & 31, bz = panel >> 5;
    gemm_body<0, 0, 0, 1, 2, 0>(
        wvo, ht + (size_t)bz * HT, vo, nullptr, nullptr, nullptr,
        1.f, 512, 512, 512, 4096, VOz, 0, bm, bn, bz, sm);
  }
}

// ---------------------------------------------------------------------------
// prep_all: segmented grid (1858 blocks x 256 thr).
// ---------------------------------------------------------------------------
__global__ __launch_bounds__(256)
void prep_all(const float* __restrict__ wq, const float* __restrict__ wk,
              const float* __restrict__ wo, const float* __restrict__ wv,
              const float* __restrict__ bv, const float* __restrict__ bo,
              const float* __restrict__ bq, const float* __restrict__ bk,
              const float* __restrict__ x,
              __hip_bfloat16* __restrict__ wbf, __hip_bfloat16* __restrict__ wvT,
              float* __restrict__ bvo, float* __restrict__ bqk,
              float* __restrict__ part)
{
  const int b = blockIdx.x, tid = threadIdx.x;
  if (b < 768) {
    const int j = b >> 8;
    const float* src = (j == 0) ? wq : (j == 1) ? wk : wo;
    const int i = (b & 255) * 256 + tid;
    float4 v = reinterpret_cast<const float4*>(src)[i];
    short4_t o;
    o[0] = f2bf_bits(v.x); o[1] = f2bf_bits(v.y);
    o[2] = f2bf_bits(v.z); o[3] = f2bf_bits(v.w);
    *reinterpret_cast<short4_t*>((short*)wbf + (size_t)j * 262144 + (size_t)i * 4) = o;
  } else if (b < 832) {
    __shared__ float tile[64][65];
    const int b2 = b - 768, ct = b2 >> 3, it = b2 & 7;
    const int lane = tid & 63, rr = tid >> 6;
#pragma unroll
    for (int p = 0; p < 16; ++p) {
      const int cl = p * 4 + rr;
      tile[cl][lane] = wv[(size_t)(ct * 64 + cl) * 512 + it * 64 + lane];
    }
    __syncthreads();
#pragma unroll
    for (int p = 0; p < 16; ++p) {
      const int il = p * 4 + rr;
      wvT[(size_t)(it * 64 + il) * 512 + ct * 64 + lane] = __float2bfloat16(tile[lane][il]);
    }
  } else if (b < 834) {
    const int o = (b - 832) * 256 + tid;   // 0..511
    const float4* row = reinterpret_cast<const float4*>(wo + (size_t)o * 512);
    const float4* b4 = reinterpret_cast<const float4*>(bv);
    float s = 0.f;
#pragma unroll 8
    for (int i = 0; i < 128; ++i) {
      float4 a = row[i], bb = b4[i];
      s += a.x * bb.x + a.y * bb.y + a.z * bb.z + a.w * bb.w;
    }
    bvo[o] = s + bo[o];
    bqk[o] = bq[o];
    bqk[512 + o] = bk[o];
  } else {
    const int b3 = b - 834;
    const int g = b3 & 31, sl = (b3 >> 5) & 15, z = b3 >> 9;
    const float* xf = x + (size_t)z * 512 * 4096 + (size_t)g * 16 * 4096 + (size_t)sl * 4096;
    const float4* px = reinterpret_cast<const float4*>(xf);
    float s = 0.f, q = 0.f;
#pragma unroll
    for (int i = 0; i < 4; ++i) {
      float4 v = px[tid + i * 256];
      s += v.x + v.y + v.z + v.w;
      q += v.x * v.x + v.y * v.y + v.z * v.z + v.w * v.w;
    }
#pragma unroll
    for (int o = 32; o; o >>= 1) { s += __shfl_xor(s, o); q += __shfl_xor(q, o); }
    __shared__ float rs[4], rq[4];
    if ((tid & 63) == 0) { rs[tid >> 6] = s; rq[tid >> 6] = q; }
    __syncthreads();
    if (tid == 0) {
      s = rs[0] + rs[1] + rs[2] + rs[3];
      q = rq[0] + rq[1] + rq[2] + rq[3];
      part[(((size_t)z * 32 + g) * 16 + sl) * 2 + 0] = s;
      part[(((size_t)z * 32 + g) * 16 + sl) * 2 + 1] = q;
    }
  }
}

// ---------------------------------------------------------------------------
// Normalize + transpose with inline stats from part (gn_finalize folded in).
// ---------------------------------------------------------------------------
__global__ __launch_bounds__(256)
void gn_apply_t(const float* __restrict__ x, const float* __restrict__ part,
                const float* __restrict__ gns, const float* __restrict__ gnb,
                __hip_bfloat16* __restrict__ ht)
{
  const int st = blockIdx.x, ct = blockIdx.y, z = blockIdx.z;
  const int tid = threadIdx.x;
  __shared__ float tile[64][65];
  __shared__ float smean[4], srstd[4];
  if (tid < 4) {
    const int g = ct * 4 + tid;
    float s = 0.f, q = 0.f;
#pragma unroll
    for (int slc = 0; slc < 16; ++slc) {
      s += part[(((size_t)z * 32 + g) * 16 + slc) * 2 + 0];
      q += part[(((size_t)z * 32 + g) * 16 + slc) * 2 + 1];
    }
    const float mean = s * (1.0f / 65536.0f);
    const float var = q * (1.0f / 65536.0f) - mean * mean;
    smean[tid] = mean;
    srstd[tid] = rsqrtf(var + 1e-6f);
  }
  __syncthreads();
  const float* xb = x + (size_t)z * 512 * 4096;
  const int lane64 = tid & 63, rr = tid >> 6;
#pragma unroll
  for (int pp = 0; pp < 16; ++pp) {
    const int cl = pp * 4 + rr;
    const int c = ct * 64 + cl;
    const float val = xb[(size_t)c * 4096 + st * 64 + lane64];
    tile[cl][lane64] = (val - smean[cl >> 4]) * srstd[cl >> 4] * gns[c] + gnb[c];
  }
  __syncthreads();
  __hip_bfloat16* hb = ht + (size_t)z * 4096 * 512;
#pragma unroll
  for (int pp = 0; pp < 16; ++pp) {
    const int sl = pp * 4 + rr;
    const int s = st * 64 + sl;
    hb[(size_t)s * 512 + ct * 64 + lane64] = __float2bfloat16(tile[lane64][sl]);
  }
}

// ---------------------------------------------------------------------------
// In-place row softmax (MODE1 fallback only).
// ---------------------------------------------------------------------------
__global__ __launch_bounds__(256)
void softmax_rows(__hip_bfloat16* __restrict__ S, long long strZ)
{
  const int row = blockIdx.x, z = blockIdx.y;
  __hip_bfloat16* p = S + (size_t)z * strZ + (size_t)row * 4096;
  const int tid = threadIdx.x;
  short8_t a = *(const short8_t*)(p + tid * 16);
  short8_t b = *(const short8_t*)(p + tid * 16 + 8);
  float v[16];
#pragma unroll
  for (int i = 0; i < 8; ++i) { v[i] = bfbits2f(a[i]); v[8 + i] = bfbits2f(b[i]); }
  float m = v[0];
#pragma unroll
  for (int i = 1; i < 16; ++i) m = fmaxf(m, v[i]);
#pragma unroll
  for (int o = 32; o; o >>= 1) m = fmaxf(m, __shfl_xor(m, o));
  __shared__ float red[8];
  if ((tid & 63) == 0) red[tid >> 6] = m;
  __syncthreads();
  m = fmaxf(fmaxf(red[0], red[1]), fmaxf(red[2], red[3]));
  float s = 0.f;
#pragma unroll
  for (int i = 0; i < 16; ++i) { v[i] = exp2f((v[i] - m) * 1.44269504f); s += v[i]; }
#pragma unroll
  for (int o = 32; o; o >>= 1) s += __shfl_xor(s, o);
  __syncthreads();
  if ((tid & 63) == 0) red[4 + (tid >> 6)] = s;
  __syncthreads();
  s = red[4] + red[5] + red[6] + red[7];
  const float inv = 1.f / s;
#pragma unroll
  for (int i = 0; i < 8; ++i) { a[i] = f2bf_bits(v[i] * inv); b[i] = f2bf_bits(v[8 + i] * inv); }
  *(short8_t*)(p + tid * 16) = a;
  *(short8_t*)(p + tid * 16 + 8) = b;
}

// ---------------------------------------------------------------------------
extern "C" void kernel_launch(void* const* d_in, const int* in_sizes, int n_in,
                              void* d_out, int out_size, void* d_ws, size_t ws_size,
                              hipStream_t stream)
{
  const float* x   = (const float*)d_in[0];
  const float* gns = (const float*)d_in[1];
  const float* gnb = (const float*)d_in[2];
  const float* wq  = (const float*)d_in[3];
  const float* bq  = (const float*)d_in[4];
  const float* wk  = (const float*)d_in[5];
  const float* bk  = (const float*)d_in[6];
  const float* wv  = (const float*)d_in[7];
  const float* bv  = (const float*)d_in[8];
  const float* wo  = (const float*)d_in[9];
  const float* bo  = (const float*)d_in[10];
  float* out = (float*)d_out;

  const int WB = 512 * 512;
  const long long HT  = 4096LL * 512;
  const long long QKz = 4096LL * 1024;
  const long long VOz = 512LL * 4096;
  const long long SS  = 4096LL * 4096;
  const long long CHW = 512LL * 4096;

  char* base = (char*)d_ws;
  size_t off = 0;
  auto alloc = [&](size_t b) { void* r = base + off; off = (off + b + 255) & ~(size_t)255; return r; };

  __hip_bfloat16* wbf = (__hip_bfloat16*)alloc((size_t)5 * WB * 2);
  float* bqk   = (float*)alloc(1024 * 4);
  float* bvo   = (float*)alloc(512 * 4);
  float* part  = (float*)alloc(2 * 32 * 16 * 2 * 4);
  float* rsum  = (float*)alloc(2 * 4096 * 4);
  float* part2 = (float*)alloc((size_t)2 * 16 * 4096 * 4);   // 512 KB
  const size_t fixed = off;

  const size_t qkB = (size_t)2 * QKz * 2;   // 16 MB
  const size_t voB = (size_t)2 * VOz * 2;   // 8 MB
  const size_t sB2 = (size_t)2 * SS * 2;    // 64 MB
  const size_t sB1 = (size_t)SS * 2;        // 32 MB
  const int MODE = (ws_size >= fixed + qkB + voB + sB2) ? 2 : 1;

  __hip_bfloat16* qk   = (__hip_bfloat16*)alloc(qkB);
  __hip_bfloat16* vo   = (__hip_bfloat16*)alloc(voB);
  const size_t sbufB = (MODE == 2) ? sB2 : sB1;
  __hip_bfloat16* sbuf = (__hip_bfloat16*)alloc(sbufB);
  // ht aliases the tail of sbuf: dead before S GEMM writes sbuf.
  __hip_bfloat16* ht = (__hip_bfloat16*)((char*)sbuf + sbufB - (size_t)2 * HT * 2);

  __hip_bfloat16* wqk = wbf;
  __hip_bfloat16* woB = wbf + 2 * WB;
  __hip_bfloat16* wvT = wbf + 3 * WB;
  __hip_bfloat16* wvo = wbf + 4 * WB;

  const float SC = 0.04419417382415922f;                 // 512^-0.5
  const float CEXP = SC * 1.4426950408889634f;           // for exp2

  prep_all<<<1858, 256, 0, stream>>>(wq, wk, wo, wv, bv, bo, bq, bk, x,
                                     wbf, wvT, bvo, bqk, part);

  // WVO[o][i] = sum_c wo[o][c] * wvT[i][c]
  gemm_nt<0, 0, 0, 1, 0, 4, 0><<<dim3(4, 4, 1), 256, 0, stream>>>(
      woB, wvT, wvo, nullptr, nullptr, nullptr, 1.f, 512, 512, 512,
      512, 512, 512, 0, 0, 0, 0);

  gn_apply_t<<<dim3(64, 8, 2), 256, 0, stream>>>(x, part, gns, gnb, ht);

  if (MODE == 2) {
    // QK + VO in one dispatch
    qkvo<<<1024, 256, 0, stream>>>(ht, wqk, wvo, qk, vo, bqk);
    // Punnorm = exp(scale * Q.K^T) + row partials
    s_gemm8<<<512, 512, 0, stream>>>(qk, sbuf, part2, CEXP);
    rs_final<<<32, 256, 0, stream>>>(part2, rsum);
    // out = (VO . P^T) * rsum + bvo + x
    gemm_nt<1, 1, 1, 1, 3, 2, 1><<<dim3(512, 1, 1), 256, 0, stream>>>(
        vo, sbuf, out, bvo, x, rsum, 1.f, 512, 4096, 4096,
        4096, 4096, 4096, VOz, SS, CHW, CHW);
  } else {
    gemm_nt<0, 2, 0, 1, 0, 4, 0><<<dim3(32, 8, 2), 256, 0, stream>>>(
        ht, wqk, qk, bqk, nullptr, nullptr, 1.f, 4096, 1024, 512,
        512, 512, 1024, HT, 0, QKz, 0);
    gemm_nt<0, 0, 0, 1, 3, 2, 0><<<dim3(512, 1, 1), 256, 0, stream>>>(
        wvo, ht, vo, nullptr, nullptr, nullptr, 1.f, 512, 4096, 512,
        512, 512, 4096, 0, HT, VOz, 0);
    for (int z = 0; z < 2; ++z) {
      gemm_nt<0, 0, 0, 0, 0, 4, 0><<<dim3(32, 32, 1), 256, 0, stream>>>(
          qk + (size_t)z * QKz, qk + (size_t)z * QKz + 512, sbuf, nullptr, nullptr,
          nullptr, SC, 4096, 4096, 512, 1024, 1024, 4096, 0, 0, 0, 0);
      softmax_rows<<<dim3(4096, 1), 256, 0, stream>>>(sbuf, 0);
      gemm_nt<1, 1, 1, 1, 0, 2, 0><<<dim3(8, 32, 1), 256, 0, stream>>>(
          vo + (size_t)z * VOz, sbuf, out + (size_t)z * CHW, bvo, x + (size_t)z * CHW,
          nullptr, 1.f, 512, 4096, 4096, 4096, 4096, 4096, 0, 0, 0, 0);
    }
  }
}